// Round 7
// baseline (312.528 us; speedup 1.0000x reference)
//
#include <hip/hip_runtime.h>

// Performer (FAVOR+) attention, MI355X, split-bf16 MFMA (hi/lo 3-pass).
// B=2 H=8 N=8192 D=64 F=256; rows R = 131072.
// Round 7: launch_bounds (256,3) on ctxK/qoK — VGPR 124/128 fits the
// 170-reg cap at 3 waves/EU (12 waves/CU, was 8). qoK back to grid 512 /
// 8 iters (per-block ctx+P fixed cost amortized; grid-1024 cost +5us in r6).

typedef __bf16 bf16;
typedef __bf16 bf16x8 __attribute__((ext_vector_type(8)));
typedef _Float16 f16;
typedef f16 f16x8 __attribute__((ext_vector_type(8)));
typedef float f32x4 __attribute__((ext_vector_type(4)));

#define N_    8192
#define BH_   16
#define NRM   0.35355339059327379f   // 64^-0.25
#define RATIO 0.0625f                // 256^-0.5
#define DSC   0.0625f                // 0.5*NRM^2
#define REPS  6.25e-6f               // RATIO*1e-4

#define CTX_W  16
#define KSUM_W (CTX_W + BH_*256*64)     // 262160
#define ZERO_W (KSUM_W + BH_*256)       // 266256

static __device__ __forceinline__ unsigned mapmax(float x){
  unsigned u=__float_as_uint(x); return (u&0x80000000u)? ~u : (u|0x80000000u);
}
static __device__ __forceinline__ float unmapmax(unsigned u){
  return __uint_as_float((u&0x80000000u)? (u&0x7fffffffu) : ~u);
}
static __device__ __forceinline__ f32x4 mfma16(bf16x8 a, bf16x8 b, f32x4 c){
  return __builtin_amdgcn_mfma_f32_16x16x32_bf16(a,b,c,0,0,0);
}
static __device__ __forceinline__ f32x4 mfma16h(f16x8 a, f16x8 b, f32x4 c){
  return __builtin_amdgcn_mfma_f32_16x16x32_f16(a,b,c,0,0,0);
}
static __device__ __forceinline__ void ld8(const float* __restrict__ p, float* x){
  float4 a=*(const float4*)p; float4 b=*(const float4*)(p+4);
  x[0]=a.x; x[1]=a.y; x[2]=a.z; x[3]=a.w; x[4]=b.x; x[5]=b.y; x[6]=b.z; x[7]=b.w;
}
static __device__ __forceinline__ void split8(const float* x, bf16x8& h, bf16x8& l){
  #pragma unroll
  for(int i=0;i<8;++i){ bf16 hi=(bf16)x[i]; h[i]=hi; l[i]=(bf16)(x[i]-(float)hi); }
}
static __device__ __forceinline__ void cvt8h(const float* x, f16x8& h){
  #pragma unroll
  for(int i=0;i<8;++i) h[i]=(f16)x[i];
}
// P-hat (NRM*P) b-fragments for a wave's 64-wide f strip: [ft 0..3][ks 0..1]
static __device__ __forceinline__ void load_P_frags(const float* __restrict__ Pg,
    int fb, int l15, int g, bf16x8 (&ph)[4][2], bf16x8 (&pl)[4][2]){
  #pragma unroll
  for(int ft=0;ft<4;++ft)
    #pragma unroll
    for(int ks=0;ks<2;++ks){
      float x[8]; ld8(&Pg[(fb+16*ft+l15)*64+32*ks+8*g],x);
      #pragma unroll
      for(int i=0;i<8;++i) x[i]*=NRM;
      split8(x,ph[ft][ks],pl[ft][ks]);
    }
}

// ---------------- kernels ----------------

__global__ void __launch_bounds__(256) initK(unsigned* ws){
  for(int i=blockIdx.x*256+threadIdx.x;i<ZERO_W;i+=gridDim.x*256) ws[i]=0u;
}

// global max of dd_k (single-f16). grid 512, 4 iters of 64 rows (P amortized).
__global__ void __launch_bounds__(256) stabK(const float* __restrict__ Kg,
                                             const float* __restrict__ Pg,
                                             unsigned* __restrict__ stab_ws){
  __shared__ float red[4];
  int tid=threadIdx.x, w=tid>>6, lane=tid&63, l15=lane&15, g=lane>>4;
  int fb=w*64;
  f16x8 pb[4][2];
  #pragma unroll
  for(int ft=0;ft<4;++ft)
    #pragma unroll
    for(int ks=0;ks<2;++ks){
      float x[8]; ld8(&Pg[(fb+16*ft+l15)*64+32*ks+8*g],x);
      #pragma unroll
      for(int i=0;i<8;++i) x[i]*=NRM;
      cvt8h(x,pb[ft][ks]);
    }
  float m=-3.4e38f;
  long base=(long)blockIdx.x*256;
  f32x4 zero={0.f,0.f,0.f,0.f};
  #pragma unroll 1
  for(int it=0;it<4;++it){
    long row0=base+it*64;
    f16x8 ka[4][2];
    #pragma unroll
    for(int rt=0;rt<4;++rt)
      #pragma unroll
      for(int ks=0;ks<2;++ks){
        float x[8]; ld8(&Kg[(row0+16*rt+l15)*64+32*ks+8*g],x);
        cvt8h(x,ka[rt][ks]);
      }
    f32x4 acc[4][4];
    #pragma unroll
    for(int rt=0;rt<4;++rt)
      #pragma unroll
      for(int ft=0;ft<4;++ft) acc[rt][ft]=zero;
    #pragma unroll
    for(int rt=0;rt<4;++rt)
      #pragma unroll
      for(int ft=0;ft<4;++ft)
        #pragma unroll
        for(int ks=0;ks<2;++ks)
          acc[rt][ft]=mfma16h(ka[rt][ks],pb[ft][ks],acc[rt][ft]);
    #pragma unroll
    for(int rt=0;rt<4;++rt)
      #pragma unroll
      for(int ft=0;ft<4;++ft)
        #pragma unroll
        for(int r=0;r<4;++r) m=fmaxf(m,acc[rt][ft][r]);
  }
  #pragma unroll
  for(int off=1;off<64;off<<=1) m=fmaxf(m,__shfl_xor(m,off));
  if(lane==0) red[w]=m;
  __syncthreads();
  if(tid==0){
    m=fmaxf(fmaxf(red[0],red[1]),fmaxf(red[2],red[3]));
    atomicMax(stab_ws,mapmax(m));
  }
}

// kp + ctx/ksum accumulation. grid = 512: 16 bh * 32 chunks of 256 rows,
// 8 iters. V raw loads hoisted before dd-GEMM. No __syncthreads.
__global__ void __launch_bounds__(256,3) ctxK(const float* __restrict__ Kg,
    const float* __restrict__ Vg, const float* __restrict__ Pg,
    const unsigned* __restrict__ stab_ws, float* __restrict__ ctx_g,
    float* __restrict__ ksum_g){
  __shared__ __align__(16) bf16 kpt_h[256*40];
  __shared__ __align__(16) bf16 kpt_l[256*40];
  int tid=threadIdx.x, w=tid>>6, lane=tid&63, l15=lane&15, g=lane>>4;
  int fb=w*64;
  int bh=blockIdx.x>>5, ch=blockIdx.x&31;
  long rowbase=(long)bh*N_ + ch*256;
  float stab=unmapmax(*stab_ws);
  bf16x8 pb_h[4][2], pb_l[4][2];
  load_P_frags(Pg,fb,l15,g,pb_h,pb_l);
  f32x4 zero={0.f,0.f,0.f,0.f};
  f32x4 cacc[4][4];
  #pragma unroll
  for(int mt=0;mt<4;++mt)
    #pragma unroll
    for(int et=0;et<4;++et) cacc[mt][et]=zero;
  float ksacc[4]={0.f,0.f,0.f,0.f};
  #pragma unroll 1
  for(int it=0;it<8;++it){
    long n0=rowbase+it*32;
    // K a-frags (split) + row sums of squares
    bf16x8 ka_h[2][2], ka_l[2][2];
    float dsq[2];
    #pragma unroll
    for(int rt=0;rt<2;++rt){
      float ss=0.f;
      #pragma unroll
      for(int ks=0;ks<2;++ks){
        float x[8]; ld8(&Kg[(n0+16*rt+l15)*64+32*ks+8*g],x);
        #pragma unroll
        for(int i=0;i<8;++i) ss=fmaf(x[i],x[i],ss);
        split8(x,ka_h[rt][ks],ka_l[rt][ks]);
      }
      ss+=__shfl_xor(ss,16); ss+=__shfl_xor(ss,32);
      dsq[rt]=DSC*ss;
    }
    // V raw prefetch (hoisted: latency hidden under dd-GEMM + exp)
    float vx[4][8];
    #pragma unroll
    for(int et=0;et<4;++et)
      #pragma unroll
      for(int j=0;j<8;++j) vx[et][j]=Vg[(n0+8*g+j)*64+16*et+l15];
    // dd = K-hat @ P-hat^T (3-pass split)
    f32x4 dacc[2][4];
    #pragma unroll
    for(int rt=0;rt<2;++rt)
      #pragma unroll
      for(int ft=0;ft<4;++ft) dacc[rt][ft]=zero;
    #pragma unroll
    for(int rt=0;rt<2;++rt)
      #pragma unroll
      for(int ft=0;ft<4;++ft)
        #pragma unroll
        for(int ks=0;ks<2;++ks){
          dacc[rt][ft]=mfma16(ka_h[rt][ks],pb_h[ft][ks],dacc[rt][ft]);
          dacc[rt][ft]=mfma16(ka_h[rt][ks],pb_l[ft][ks],dacc[rt][ft]);
          dacc[rt][ft]=mfma16(ka_l[rt][ks],pb_h[ft][ks],dacc[rt][ft]);
        }
    float dg[2][4];
    #pragma unroll
    for(int rt=0;rt<2;++rt)
      #pragma unroll
      for(int r=0;r<4;++r) dg[rt][r]=__shfl(dsq[rt],4*g+r);
    // kp = RATIO*exp(dd - diag - stab) + REPS; write transposed [f][n] hi/lo
    #pragma unroll
    for(int rt=0;rt<2;++rt)
      #pragma unroll
      for(int ft=0;ft<4;++ft){
        int f=fb+16*ft+l15;
        #pragma unroll
        for(int r=0;r<4;++r){
          float kp=fmaf(RATIO,__expf(dacc[rt][ft][r]-dg[rt][r]-stab),REPS);
          ksacc[ft]+=kp;
          bf16 hb=(bf16)kp; bf16 lb=(bf16)(kp-(float)hb);
          int nn=16*rt+4*g+r;
          kpt_h[f*40+nn]=hb; kpt_l[f*40+nn]=lb;
        }
      }
    // V b-frags (split from prefetched registers)
    bf16x8 vb_h[4], vb_l[4];
    #pragma unroll
    for(int et=0;et<4;++et) split8(vx[et],vb_h[et],vb_l[et]);
    // ctx += kp^T @ V (3-pass split); kpt is wave-local (same-wave RAW only)
    #pragma unroll
    for(int mt=0;mt<4;++mt){
      bf16x8 a_h=*(const bf16x8*)&kpt_h[(fb+16*mt+l15)*40+8*g];
      bf16x8 a_l=*(const bf16x8*)&kpt_l[(fb+16*mt+l15)*40+8*g];
      #pragma unroll
      for(int et=0;et<4;++et){
        cacc[mt][et]=mfma16(a_h,vb_h[et],cacc[mt][et]);
        cacc[mt][et]=mfma16(a_h,vb_l[et],cacc[mt][et]);
        cacc[mt][et]=mfma16(a_l,vb_h[et],cacc[mt][et]);
      }
    }
  }
  float* cg=ctx_g+(long)bh*16384;
  #pragma unroll
  for(int mt=0;mt<4;++mt)
    #pragma unroll
    for(int et=0;et<4;++et)
      #pragma unroll
      for(int r=0;r<4;++r)
        atomicAdd(&cg[(fb+16*mt+4*g+r)*64+16*et+l15],cacc[mt][et][r]);
  #pragma unroll
  for(int ft=0;ft<4;++ft){
    float s=ksacc[ft];
    s+=__shfl_xor(s,16); s+=__shfl_xor(s,32);
    if(g==0) atomicAdd(&ksum_g[bh*256+fb+16*ft+l15],s);
  }
}

// fused qp + out. grid = 512: bh = blk&15 (XCD-local), 32 chunks of 256 rows,
// 8 iters (per-block ctx/P fixed cost amortized).
__global__ void __launch_bounds__(256,3) qoK(const float* __restrict__ Qg,
    const float* __restrict__ Pg, const float* __restrict__ ctx_g,
    const float* __restrict__ ksum_g, float* __restrict__ outg){
  __shared__ float qpt_h[32*132];   // packed bf16 pairs (hi plane), [n][f/2]
  __shared__ float qpt_l[32*132];   // lo plane
  __shared__ float rmaxl[4][32];
  __shared__ float denl[4][32];
  int tid=threadIdx.x, w=tid>>6, lane=tid&63, l15=lane&15, g=lane>>4;
  int fb=w*64;
  int bh=blockIdx.x&15, ch=blockIdx.x>>4;
  long rowbase=(long)bh*N_ + ch*256;
  bf16x8 pb_h[4][2], pb_l[4][2];
  load_P_frags(Pg,fb,l15,g,pb_h,pb_l);
  float ksv[4];
  #pragma unroll
  for(int ft=0;ft<4;++ft) ksv[ft]=ksum_g[bh*256+fb+16*ft+l15];
  // ctx b-frags for this wave's e-tile (et = w), split
  bf16x8 cb_h[8], cb_l[8];
  #pragma unroll
  for(int ks=0;ks<8;++ks){
    float x[8];
    #pragma unroll
    for(int j=0;j<8;++j) x[j]=ctx_g[(long)bh*16384+(32*ks+8*g+j)*64+16*w+l15];
    split8(x,cb_h[ks],cb_l[ks]);
  }
  f32x4 zero={0.f,0.f,0.f,0.f};
  #pragma unroll 1
  for(int it=0;it<8;++it){
    long n0=rowbase+it*32;
    // Q a-frags (split) + diag
    bf16x8 qa_h[2][2], qa_l[2][2];
    float dsq[2];
    #pragma unroll
    for(int rt=0;rt<2;++rt){
      float ss=0.f;
      #pragma unroll
      for(int ks=0;ks<2;++ks){
        float x[8]; ld8(&Qg[(n0+16*rt+l15)*64+32*ks+8*g],x);
        #pragma unroll
        for(int i=0;i<8;++i) ss=fmaf(x[i],x[i],ss);
        split8(x,qa_h[rt][ks],qa_l[rt][ks]);
      }
      ss+=__shfl_xor(ss,16); ss+=__shfl_xor(ss,32);
      dsq[rt]=DSC*ss;
    }
    f32x4 dacc[2][4];
    #pragma unroll
    for(int rt=0;rt<2;++rt)
      #pragma unroll
      for(int ft=0;ft<4;++ft) dacc[rt][ft]=zero;
    #pragma unroll
    for(int rt=0;rt<2;++rt)
      #pragma unroll
      for(int ft=0;ft<4;++ft)
        #pragma unroll
        for(int ks=0;ks<2;++ks){
          dacc[rt][ft]=mfma16(qa_h[rt][ks],pb_h[ft][ks],dacc[rt][ft]);
          dacc[rt][ft]=mfma16(qa_h[rt][ks],pb_l[ft][ks],dacc[rt][ft]);
          dacc[rt][ft]=mfma16(qa_l[rt][ks],pb_h[ft][ks],dacc[rt][ft]);
        }
    float dg[2][4];
    #pragma unroll
    for(int rt=0;rt<2;++rt)
      #pragma unroll
      for(int r=0;r<4;++r) dg[rt][r]=__shfl(dsq[rt],4*g+r);
    // per-wave rowmax over its f-strip
    #pragma unroll
    for(int rt=0;rt<2;++rt)
      #pragma unroll
      for(int r=0;r<4;++r){
        float m=fmaxf(fmaxf(dacc[rt][0][r],dacc[rt][1][r]),
                      fmaxf(dacc[rt][2][r],dacc[rt][3][r]));
        m=fmaxf(m,__shfl_xor(m,1)); m=fmaxf(m,__shfl_xor(m,2));
        m=fmaxf(m,__shfl_xor(m,4)); m=fmaxf(m,__shfl_xor(m,8));
        if(l15==0) rmaxl[w][16*rt+4*g+r]=m;
      }
    __syncthreads();   // rowmax planes ready
    // qp, den partials, packed qpt writes
    #pragma unroll
    for(int rt=0;rt<2;++rt)
      #pragma unroll
      for(int r=0;r<4;++r){
        int nn=16*rt+4*g+r;
        float rm=fmaxf(fmaxf(rmaxl[0][nn],rmaxl[1][nn]),
                       fmaxf(rmaxl[2][nn],rmaxl[3][nn]));
        float dp=0.f;
        #pragma unroll
        for(int ft=0;ft<4;++ft){
          float qp=fmaf(RATIO,__expf(dacc[rt][ft][r]-dg[rt][r]-rm),REPS);
          dp=fmaf(qp,ksv[ft],dp);
          bf16 hb=(bf16)qp; bf16 lb=(bf16)(qp-(float)hb);
          unsigned mine=(unsigned)__builtin_bit_cast(unsigned short,hb)
                       |((unsigned)__builtin_bit_cast(unsigned short,lb)<<16);
          unsigned other=(unsigned)__shfl_xor((int)mine,1);
          int f=fb+16*ft+l15;
          unsigned wv=(lane&1)? ((other>>16)|(mine&0xffff0000u))
                              : ((mine&0xffffu)|(other<<16));
          float* bp=(lane&1)? qpt_l : qpt_h;
          bp[nn*132+(f>>1)]=__uint_as_float(wv);
        }
        dp+=__shfl_xor(dp,1); dp+=__shfl_xor(dp,2);
        dp+=__shfl_xor(dp,4); dp+=__shfl_xor(dp,8);
        if(l15==0) denl[w][nn]=dp;
      }
    __syncthreads();   // qpt + denl ready
    // out = qp @ ctx (3-pass split), this wave's e-tile
    f32x4 oacc[2]; oacc[0]=zero; oacc[1]=zero;
    #pragma unroll
    for(int ks=0;ks<8;++ks)
      #pragma unroll
      for(int mt=0;mt<2;++mt){
        bf16x8 a_h=*(const bf16x8*)&qpt_h[(16*mt+l15)*132+16*ks+4*g];
        bf16x8 a_l=*(const bf16x8*)&qpt_l[(16*mt+l15)*132+16*ks+4*g];
        oacc[mt]=mfma16(a_h,cb_h[ks],oacc[mt]);
        oacc[mt]=mfma16(a_h,cb_l[ks],oacc[mt]);
        oacc[mt]=mfma16(a_l,cb_h[ks],oacc[mt]);
      }
    #pragma unroll
    for(int mt=0;mt<2;++mt)
      #pragma unroll
      for(int r=0;r<4;++r){
        int nn=16*mt+4*g+r;
        float den=denl[0][nn]+denl[1][nn]+denl[2][nn]+denl[3][nn];
        outg[(n0+nn)*64+16*w+l15]=oacc[mt][r]/den;
      }
    __syncthreads();   // qpt consumed; safe to overwrite next iter
  }
}

// ---------------- host ----------------

extern "C" void kernel_launch(void* const* d_in, const int* in_sizes, int n_in,
                              void* d_out, int out_size, void* d_ws, size_t ws_size,
                              hipStream_t stream) {
  (void)in_sizes; (void)n_in; (void)out_size; (void)ws_size;
  const float* q = (const float*)d_in[0];
  const float* k = (const float*)d_in[1];
  const float* v = (const float*)d_in[2];
  const float* P = (const float*)d_in[3];
  float* out = (float*)d_out;

  unsigned* stab = (unsigned*)d_ws;
  float* ctx  = (float*)d_ws + CTX_W;
  float* ksum = (float*)d_ws + KSUM_W;

  hipLaunchKernelGGL(initK, dim3(256), dim3(256), 0, stream, (unsigned*)d_ws);
  hipLaunchKernelGGL(stabK, dim3(512), dim3(256), 0, stream, k, P, stab);
  hipLaunchKernelGGL(ctxK, dim3(512), dim3(256), 0, stream, k, v, P, stab, ctx, ksum);
  hipLaunchKernelGGL(qoK, dim3(512), dim3(256), 0, stream, q, P, ctx, ksum, out);
}

// Round 8
// 163.527 us; speedup vs baseline: 1.9112x; 1.9112x over previous
//
#include <hip/hip_runtime.h>

// Performer (FAVOR+) attention, MI355X, split-bf16 MFMA.
// B=2 H=8 N=8192 D=64 F=256; rows R = 131072.
// Round 8: revert to round-6 launch config ((256,2), ctxK/qoK grid 512,
// 8 iters — r7's (256,3) spilled: true reg budget is VGPR+AGPR vs 512/waves,
// 84 arch-VGPR cap -> 245MB scratch traffic). New: qp/kp stored as SINGLE
// bf16 (consistent numerator+denominator => exact formula on perturbed
// features; err ~1e-4). Drops lo LDS planes, 8 MFMA/iter in qoK and
// 16 MFMA/iter in ctxK, half the pack VALU. K/Q/P/V/ctx stay split-precision.

typedef __bf16 bf16;
typedef __bf16 bf16x8 __attribute__((ext_vector_type(8)));
typedef _Float16 f16;
typedef f16 f16x8 __attribute__((ext_vector_type(8)));
typedef float f32x4 __attribute__((ext_vector_type(4)));

#define N_    8192
#define BH_   16
#define NRM   0.35355339059327379f   // 64^-0.25
#define RATIO 0.0625f                // 256^-0.5
#define DSC   0.0625f                // 0.5*NRM^2
#define REPS  6.25e-6f               // RATIO*1e-4

#define CTX_W  16
#define KSUM_W (CTX_W + BH_*256*64)     // 262160
#define ZERO_W (KSUM_W + BH_*256)       // 266256

static __device__ __forceinline__ unsigned mapmax(float x){
  unsigned u=__float_as_uint(x); return (u&0x80000000u)? ~u : (u|0x80000000u);
}
static __device__ __forceinline__ float unmapmax(unsigned u){
  return __uint_as_float((u&0x80000000u)? (u&0x7fffffffu) : ~u);
}
static __device__ __forceinline__ f32x4 mfma16(bf16x8 a, bf16x8 b, f32x4 c){
  return __builtin_amdgcn_mfma_f32_16x16x32_bf16(a,b,c,0,0,0);
}
static __device__ __forceinline__ f32x4 mfma16h(f16x8 a, f16x8 b, f32x4 c){
  return __builtin_amdgcn_mfma_f32_16x16x32_f16(a,b,c,0,0,0);
}
static __device__ __forceinline__ void ld8(const float* __restrict__ p, float* x){
  float4 a=*(const float4*)p; float4 b=*(const float4*)(p+4);
  x[0]=a.x; x[1]=a.y; x[2]=a.z; x[3]=a.w; x[4]=b.x; x[5]=b.y; x[6]=b.z; x[7]=b.w;
}
static __device__ __forceinline__ void split8(const float* x, bf16x8& h, bf16x8& l){
  #pragma unroll
  for(int i=0;i<8;++i){ bf16 hi=(bf16)x[i]; h[i]=hi; l[i]=(bf16)(x[i]-(float)hi); }
}
static __device__ __forceinline__ void cvt8h(const float* x, f16x8& h){
  #pragma unroll
  for(int i=0;i<8;++i) h[i]=(f16)x[i];
}
// P-hat (NRM*P) b-fragments for a wave's 64-wide f strip: [ft 0..3][ks 0..1]
static __device__ __forceinline__ void load_P_frags(const float* __restrict__ Pg,
    int fb, int l15, int g, bf16x8 (&ph)[4][2], bf16x8 (&pl)[4][2]){
  #pragma unroll
  for(int ft=0;ft<4;++ft)
    #pragma unroll
    for(int ks=0;ks<2;++ks){
      float x[8]; ld8(&Pg[(fb+16*ft+l15)*64+32*ks+8*g],x);
      #pragma unroll
      for(int i=0;i<8;++i) x[i]*=NRM;
      split8(x,ph[ft][ks],pl[ft][ks]);
    }
}

// ---------------- kernels ----------------

__global__ void __launch_bounds__(256) initK(unsigned* ws){
  for(int i=blockIdx.x*256+threadIdx.x;i<ZERO_W;i+=gridDim.x*256) ws[i]=0u;
}

// global max of dd_k (single-f16). grid 512, 4 iters of 64 rows (P amortized).
__global__ void __launch_bounds__(256) stabK(const float* __restrict__ Kg,
                                             const float* __restrict__ Pg,
                                             unsigned* __restrict__ stab_ws){
  __shared__ float red[4];
  int tid=threadIdx.x, w=tid>>6, lane=tid&63, l15=lane&15, g=lane>>4;
  int fb=w*64;
  f16x8 pb[4][2];
  #pragma unroll
  for(int ft=0;ft<4;++ft)
    #pragma unroll
    for(int ks=0;ks<2;++ks){
      float x[8]; ld8(&Pg[(fb+16*ft+l15)*64+32*ks+8*g],x);
      #pragma unroll
      for(int i=0;i<8;++i) x[i]*=NRM;
      cvt8h(x,pb[ft][ks]);
    }
  float m=-3.4e38f;
  long base=(long)blockIdx.x*256;
  f32x4 zero={0.f,0.f,0.f,0.f};
  #pragma unroll 1
  for(int it=0;it<4;++it){
    long row0=base+it*64;
    f16x8 ka[4][2];
    #pragma unroll
    for(int rt=0;rt<4;++rt)
      #pragma unroll
      for(int ks=0;ks<2;++ks){
        float x[8]; ld8(&Kg[(row0+16*rt+l15)*64+32*ks+8*g],x);
        cvt8h(x,ka[rt][ks]);
      }
    f32x4 acc[4][4];
    #pragma unroll
    for(int rt=0;rt<4;++rt)
      #pragma unroll
      for(int ft=0;ft<4;++ft) acc[rt][ft]=zero;
    #pragma unroll
    for(int rt=0;rt<4;++rt)
      #pragma unroll
      for(int ft=0;ft<4;++ft)
        #pragma unroll
        for(int ks=0;ks<2;++ks)
          acc[rt][ft]=mfma16h(ka[rt][ks],pb[ft][ks],acc[rt][ft]);
    #pragma unroll
    for(int rt=0;rt<4;++rt)
      #pragma unroll
      for(int ft=0;ft<4;++ft)
        #pragma unroll
        for(int r=0;r<4;++r) m=fmaxf(m,acc[rt][ft][r]);
  }
  #pragma unroll
  for(int off=1;off<64;off<<=1) m=fmaxf(m,__shfl_xor(m,off));
  if(lane==0) red[w]=m;
  __syncthreads();
  if(tid==0){
    m=fmaxf(fmaxf(red[0],red[1]),fmaxf(red[2],red[3]));
    atomicMax(stab_ws,mapmax(m));
  }
}

// kp + ctx/ksum accumulation. grid = 512: 16 bh * 32 chunks of 256 rows,
// 8 iters. V raw loads hoisted before dd-GEMM. kp single-bf16 (consistent
// with ksum). No __syncthreads: kpt LDS regions are wave-local.
__global__ void __launch_bounds__(256,2) ctxK(const float* __restrict__ Kg,
    const float* __restrict__ Vg, const float* __restrict__ Pg,
    const unsigned* __restrict__ stab_ws, float* __restrict__ ctx_g,
    float* __restrict__ ksum_g){
  __shared__ __align__(16) bf16 kpt_h[256*40];
  int tid=threadIdx.x, w=tid>>6, lane=tid&63, l15=lane&15, g=lane>>4;
  int fb=w*64;
  int bh=blockIdx.x>>5, ch=blockIdx.x&31;
  long rowbase=(long)bh*N_ + ch*256;
  float stab=unmapmax(*stab_ws);
  bf16x8 pb_h[4][2], pb_l[4][2];
  load_P_frags(Pg,fb,l15,g,pb_h,pb_l);
  f32x4 zero={0.f,0.f,0.f,0.f};
  f32x4 cacc[4][4];
  #pragma unroll
  for(int mt=0;mt<4;++mt)
    #pragma unroll
    for(int et=0;et<4;++et) cacc[mt][et]=zero;
  float ksacc[4]={0.f,0.f,0.f,0.f};
  #pragma unroll 1
  for(int it=0;it<8;++it){
    long n0=rowbase+it*32;
    // K a-frags (split) + row sums of squares
    bf16x8 ka_h[2][2], ka_l[2][2];
    float dsq[2];
    #pragma unroll
    for(int rt=0;rt<2;++rt){
      float ss=0.f;
      #pragma unroll
      for(int ks=0;ks<2;++ks){
        float x[8]; ld8(&Kg[(n0+16*rt+l15)*64+32*ks+8*g],x);
        #pragma unroll
        for(int i=0;i<8;++i) ss=fmaf(x[i],x[i],ss);
        split8(x,ka_h[rt][ks],ka_l[rt][ks]);
      }
      ss+=__shfl_xor(ss,16); ss+=__shfl_xor(ss,32);
      dsq[rt]=DSC*ss;
    }
    // V raw prefetch (hoisted: latency hidden under dd-GEMM + exp)
    float vx[4][8];
    #pragma unroll
    for(int et=0;et<4;++et)
      #pragma unroll
      for(int j=0;j<8;++j) vx[et][j]=Vg[(n0+8*g+j)*64+16*et+l15];
    // dd = K-hat @ P-hat^T (3-pass split)
    f32x4 dacc[2][4];
    #pragma unroll
    for(int rt=0;rt<2;++rt)
      #pragma unroll
      for(int ft=0;ft<4;++ft) dacc[rt][ft]=zero;
    #pragma unroll
    for(int rt=0;rt<2;++rt)
      #pragma unroll
      for(int ft=0;ft<4;++ft)
        #pragma unroll
        for(int ks=0;ks<2;++ks){
          dacc[rt][ft]=mfma16(ka_h[rt][ks],pb_h[ft][ks],dacc[rt][ft]);
          dacc[rt][ft]=mfma16(ka_h[rt][ks],pb_l[ft][ks],dacc[rt][ft]);
          dacc[rt][ft]=mfma16(ka_l[rt][ks],pb_h[ft][ks],dacc[rt][ft]);
        }
    float dg[2][4];
    #pragma unroll
    for(int rt=0;rt<2;++rt)
      #pragma unroll
      for(int r=0;r<4;++r) dg[rt][r]=__shfl(dsq[rt],4*g+r);
    // kp = RATIO*exp(dd - diag - stab) + REPS, rounded to bf16;
    // ksum accumulates the SAME rounded value (consistent features).
    #pragma unroll
    for(int rt=0;rt<2;++rt)
      #pragma unroll
      for(int ft=0;ft<4;++ft){
        int f=fb+16*ft+l15;
        #pragma unroll
        for(int r=0;r<4;++r){
          float kp=fmaf(RATIO,__expf(dacc[rt][ft][r]-dg[rt][r]-stab),REPS);
          bf16 hb=(bf16)kp;
          ksacc[ft]+=(float)hb;
          int nn=16*rt+4*g+r;
          kpt_h[f*40+nn]=hb;
        }
      }
    // V b-frags (split from prefetched registers)
    bf16x8 vb_h[4], vb_l[4];
    #pragma unroll
    for(int et=0;et<4;++et) split8(vx[et],vb_h[et],vb_l[et]);
    // ctx += kp_b^T @ V (kp single-plane x V split = 2-pass)
    #pragma unroll
    for(int mt=0;mt<4;++mt){
      bf16x8 a_h=*(const bf16x8*)&kpt_h[(fb+16*mt+l15)*40+8*g];
      #pragma unroll
      for(int et=0;et<4;++et){
        cacc[mt][et]=mfma16(a_h,vb_h[et],cacc[mt][et]);
        cacc[mt][et]=mfma16(a_h,vb_l[et],cacc[mt][et]);
      }
    }
  }
  float* cg=ctx_g+(long)bh*16384;
  #pragma unroll
  for(int mt=0;mt<4;++mt)
    #pragma unroll
    for(int et=0;et<4;++et)
      #pragma unroll
      for(int r=0;r<4;++r)
        atomicAdd(&cg[(fb+16*mt+4*g+r)*64+16*et+l15],cacc[mt][et][r]);
  #pragma unroll
  for(int ft=0;ft<4;++ft){
    float s=ksacc[ft];
    s+=__shfl_xor(s,16); s+=__shfl_xor(s,32);
    if(g==0) atomicAdd(&ksum_g[bh*256+fb+16*ft+l15],s);
  }
}

// fused qp + out. grid = 512: 16 bh * 32 chunks of 256 rows, 8 iters.
// qp single-bf16, used consistently in numerator (qp@ctx) and
// denominator (qp.ksum).
__global__ void __launch_bounds__(256,2) qoK(const float* __restrict__ Qg,
    const float* __restrict__ Pg, const float* __restrict__ ctx_g,
    const float* __restrict__ ksum_g, float* __restrict__ outg){
  __shared__ float qpt_h[32*132];   // packed bf16 pairs, [n][f/2]
  __shared__ float rmaxl[4][32];
  __shared__ float denl[4][32];
  int tid=threadIdx.x, w=tid>>6, lane=tid&63, l15=lane&15, g=lane>>4;
  int fb=w*64;
  int bh=blockIdx.x>>5, ch=blockIdx.x&31;
  long rowbase=(long)bh*N_ + ch*256;
  bf16x8 pb_h[4][2], pb_l[4][2];
  load_P_frags(Pg,fb,l15,g,pb_h,pb_l);
  float ksv[4];
  #pragma unroll
  for(int ft=0;ft<4;++ft) ksv[ft]=ksum_g[bh*256+fb+16*ft+l15];
  // ctx b-frags for this wave's e-tile (et = w), split
  bf16x8 cb_h[8], cb_l[8];
  #pragma unroll
  for(int ks=0;ks<8;++ks){
    float x[8];
    #pragma unroll
    for(int j=0;j<8;++j) x[j]=ctx_g[(long)bh*16384+(32*ks+8*g+j)*64+16*w+l15];
    split8(x,cb_h[ks],cb_l[ks]);
  }
  f32x4 zero={0.f,0.f,0.f,0.f};
  #pragma unroll 1
  for(int it=0;it<8;++it){
    long n0=rowbase+it*32;
    // Q a-frags (split) + diag
    bf16x8 qa_h[2][2], qa_l[2][2];
    float dsq[2];
    #pragma unroll
    for(int rt=0;rt<2;++rt){
      float ss=0.f;
      #pragma unroll
      for(int ks=0;ks<2;++ks){
        float x[8]; ld8(&Qg[(n0+16*rt+l15)*64+32*ks+8*g],x);
        #pragma unroll
        for(int i=0;i<8;++i) ss=fmaf(x[i],x[i],ss);
        split8(x,qa_h[rt][ks],qa_l[rt][ks]);
      }
      ss+=__shfl_xor(ss,16); ss+=__shfl_xor(ss,32);
      dsq[rt]=DSC*ss;
    }
    f32x4 dacc[2][4];
    #pragma unroll
    for(int rt=0;rt<2;++rt)
      #pragma unroll
      for(int ft=0;ft<4;++ft) dacc[rt][ft]=zero;
    #pragma unroll
    for(int rt=0;rt<2;++rt)
      #pragma unroll
      for(int ft=0;ft<4;++ft)
        #pragma unroll
        for(int ks=0;ks<2;++ks){
          dacc[rt][ft]=mfma16(qa_h[rt][ks],pb_h[ft][ks],dacc[rt][ft]);
          dacc[rt][ft]=mfma16(qa_h[rt][ks],pb_l[ft][ks],dacc[rt][ft]);
          dacc[rt][ft]=mfma16(qa_l[rt][ks],pb_h[ft][ks],dacc[rt][ft]);
        }
    float dg[2][4];
    #pragma unroll
    for(int rt=0;rt<2;++rt)
      #pragma unroll
      for(int r=0;r<4;++r) dg[rt][r]=__shfl(dsq[rt],4*g+r);
    // per-wave rowmax over its f-strip
    #pragma unroll
    for(int rt=0;rt<2;++rt)
      #pragma unroll
      for(int r=0;r<4;++r){
        float m=fmaxf(fmaxf(dacc[rt][0][r],dacc[rt][1][r]),
                      fmaxf(dacc[rt][2][r],dacc[rt][3][r]));
        m=fmaxf(m,__shfl_xor(m,1)); m=fmaxf(m,__shfl_xor(m,2));
        m=fmaxf(m,__shfl_xor(m,4)); m=fmaxf(m,__shfl_xor(m,8));
        if(l15==0) rmaxl[w][16*rt+4*g+r]=m;
      }
    __syncthreads();   // rowmax planes ready
    // qp (rounded bf16), den partials from the SAME rounded value,
    // packed qpt writes (even lanes pack [f, f+1] into one dword).
    #pragma unroll
    for(int rt=0;rt<2;++rt)
      #pragma unroll
      for(int r=0;r<4;++r){
        int nn=16*rt+4*g+r;
        float rm=fmaxf(fmaxf(rmaxl[0][nn],rmaxl[1][nn]),
                       fmaxf(rmaxl[2][nn],rmaxl[3][nn]));
        float dp=0.f;
        #pragma unroll
        for(int ft=0;ft<4;++ft){
          float qp=fmaf(RATIO,__expf(dacc[rt][ft][r]-dg[rt][r]-rm),REPS);
          bf16 hb=(bf16)qp;
          dp=fmaf((float)hb,ksv[ft],dp);
          unsigned mine=(unsigned)__builtin_bit_cast(unsigned short,hb);
          unsigned other=(unsigned)__shfl_xor((int)mine,1);
          if(!(lane&1)){
            int f=fb+16*ft+l15;
            qpt_h[nn*132+(f>>1)]=__uint_as_float(mine|(other<<16));
          }
        }
        dp+=__shfl_xor(dp,1); dp+=__shfl_xor(dp,2);
        dp+=__shfl_xor(dp,4); dp+=__shfl_xor(dp,8);
        if(l15==0) denl[w][nn]=dp;
      }
    __syncthreads();   // qpt + denl ready
    // out = qp_b @ ctx (single-plane qp x split ctx = 2-pass)
    f32x4 oacc[2]; oacc[0]=zero; oacc[1]=zero;
    #pragma unroll
    for(int ks=0;ks<8;++ks)
      #pragma unroll
      for(int mt=0;mt<2;++mt){
        bf16x8 a_h=*(const bf16x8*)&qpt_h[(16*mt+l15)*132+16*ks+4*g];
        oacc[mt]=mfma16(a_h,cb_h[ks],oacc[mt]);
        oacc[mt]=mfma16(a_h,cb_l[ks],oacc[mt]);
      }
    #pragma unroll
    for(int mt=0;mt<2;++mt)
      #pragma unroll
      for(int r=0;r<4;++r){
        int nn=16*mt+4*g+r;
        float den=denl[0][nn]+denl[1][nn]+denl[2][nn]+denl[3][nn];
        outg[(n0+nn)*64+16*w+l15]=oacc[mt][r]/den;
      }
  }
}

// ---------------- host ----------------

extern "C" void kernel_launch(void* const* d_in, const int* in_sizes, int n_in,
                              void* d_out, int out_size, void* d_ws, size_t ws_size,
                              hipStream_t stream) {
  (void)in_sizes; (void)n_in; (void)out_size; (void)ws_size;
  const float* q = (const float*)d_in[0];
  const float* k = (const float*)d_in[1];
  const float* v = (const float*)d_in[2];
  const float* P = (const float*)d_in[3];
  float* out = (float*)d_out;

  unsigned* stab = (unsigned*)d_ws;
  float* ctx  = (float*)d_ws + CTX_W;
  float* ksum = (float*)d_ws + KSUM_W;

  hipLaunchKernelGGL(initK, dim3(256), dim3(256), 0, stream, (unsigned*)d_ws);
  hipLaunchKernelGGL(stabK, dim3(512), dim3(256), 0, stream, k, P, stab);
  hipLaunchKernelGGL(ctxK, dim3(512), dim3(256), 0, stream, k, v, P, stab, ctx, ksum);
  hipLaunchKernelGGL(qoK, dim3(512), dim3(256), 0, stream, q, P, ctx, ksum, out);
}

// Round 9
// 150.331 us; speedup vs baseline: 2.0789x; 1.0878x over previous
//
#include <hip/hip_runtime.h>

// Performer (FAVOR+) attention, MI355X, split-bf16 MFMA.
// B=2 H=8 N=8192 D=64 F=256; rows R = 131072.
// Round 9 (qoK only — r8 showed qoK is latency-bound, work removal was free):
//  * Q staged into LDS double-buffer via global_load_lds(16B): next tile
//    issued at iter top, existing barriers drain vmcnt -> 0 extra VGPRs,
//    ~600cy/iter of exposed global latency removed from the serial chain.
//    XOR-swizzled source (T2/m173 pattern) so frag ds_read_b128s are ~conflict-free.
//  * qp pack-shfls (32/iter) removed: direct ds_write_b16 into bf16 [n][264].
// ctxK/stabK/initK unchanged from round 8.

typedef __bf16 bf16;
typedef __bf16 bf16x8 __attribute__((ext_vector_type(8)));
typedef _Float16 f16;
typedef f16 f16x8 __attribute__((ext_vector_type(8)));
typedef float f32x4 __attribute__((ext_vector_type(4)));

#define N_    8192
#define BH_   16
#define NRM   0.35355339059327379f   // 64^-0.25
#define RATIO 0.0625f                // 256^-0.5
#define DSC   0.0625f                // 0.5*NRM^2
#define REPS  6.25e-6f               // RATIO*1e-4

#define CTX_W  16
#define KSUM_W (CTX_W + BH_*256*64)     // 262160
#define ZERO_W (KSUM_W + BH_*256)       // 266256

static __device__ __forceinline__ unsigned mapmax(float x){
  unsigned u=__float_as_uint(x); return (u&0x80000000u)? ~u : (u|0x80000000u);
}
static __device__ __forceinline__ float unmapmax(unsigned u){
  return __uint_as_float((u&0x80000000u)? (u&0x7fffffffu) : ~u);
}
static __device__ __forceinline__ f32x4 mfma16(bf16x8 a, bf16x8 b, f32x4 c){
  return __builtin_amdgcn_mfma_f32_16x16x32_bf16(a,b,c,0,0,0);
}
static __device__ __forceinline__ f32x4 mfma16h(f16x8 a, f16x8 b, f32x4 c){
  return __builtin_amdgcn_mfma_f32_16x16x32_f16(a,b,c,0,0,0);
}
static __device__ __forceinline__ void ld8(const float* __restrict__ p, float* x){
  float4 a=*(const float4*)p; float4 b=*(const float4*)(p+4);
  x[0]=a.x; x[1]=a.y; x[2]=a.z; x[3]=a.w; x[4]=b.x; x[5]=b.y; x[6]=b.z; x[7]=b.w;
}
static __device__ __forceinline__ void split8(const float* x, bf16x8& h, bf16x8& l){
  #pragma unroll
  for(int i=0;i<8;++i){ bf16 hi=(bf16)x[i]; h[i]=hi; l[i]=(bf16)(x[i]-(float)hi); }
}
static __device__ __forceinline__ void cvt8h(const float* x, f16x8& h){
  #pragma unroll
  for(int i=0;i<8;++i) h[i]=(f16)x[i];
}
static __device__ __forceinline__ void gload16(const float* g, float* l){
  __builtin_amdgcn_global_load_lds(
      (const __attribute__((address_space(1))) unsigned*)g,
      (__attribute__((address_space(3))) unsigned*)l, 16, 0, 0);
}
// P-hat (NRM*P) b-fragments for a wave's 64-wide f strip: [ft 0..3][ks 0..1]
static __device__ __forceinline__ void load_P_frags(const float* __restrict__ Pg,
    int fb, int l15, int g, bf16x8 (&ph)[4][2], bf16x8 (&pl)[4][2]){
  #pragma unroll
  for(int ft=0;ft<4;++ft)
    #pragma unroll
    for(int ks=0;ks<2;++ks){
      float x[8]; ld8(&Pg[(fb+16*ft+l15)*64+32*ks+8*g],x);
      #pragma unroll
      for(int i=0;i<8;++i) x[i]*=NRM;
      split8(x,ph[ft][ks],pl[ft][ks]);
    }
}

// ---------------- kernels ----------------

__global__ void __launch_bounds__(256) initK(unsigned* ws){
  for(int i=blockIdx.x*256+threadIdx.x;i<ZERO_W;i+=gridDim.x*256) ws[i]=0u;
}

// global max of dd_k (single-f16). grid 512, 4 iters of 64 rows (P amortized).
__global__ void __launch_bounds__(256) stabK(const float* __restrict__ Kg,
                                             const float* __restrict__ Pg,
                                             unsigned* __restrict__ stab_ws){
  __shared__ float red[4];
  int tid=threadIdx.x, w=tid>>6, lane=tid&63, l15=lane&15, g=lane>>4;
  int fb=w*64;
  f16x8 pb[4][2];
  #pragma unroll
  for(int ft=0;ft<4;++ft)
    #pragma unroll
    for(int ks=0;ks<2;++ks){
      float x[8]; ld8(&Pg[(fb+16*ft+l15)*64+32*ks+8*g],x);
      #pragma unroll
      for(int i=0;i<8;++i) x[i]*=NRM;
      cvt8h(x,pb[ft][ks]);
    }
  float m=-3.4e38f;
  long base=(long)blockIdx.x*256;
  f32x4 zero={0.f,0.f,0.f,0.f};
  #pragma unroll 1
  for(int it=0;it<4;++it){
    long row0=base+it*64;
    f16x8 ka[4][2];
    #pragma unroll
    for(int rt=0;rt<4;++rt)
      #pragma unroll
      for(int ks=0;ks<2;++ks){
        float x[8]; ld8(&Kg[(row0+16*rt+l15)*64+32*ks+8*g],x);
        cvt8h(x,ka[rt][ks]);
      }
    f32x4 acc[4][4];
    #pragma unroll
    for(int rt=0;rt<4;++rt)
      #pragma unroll
      for(int ft=0;ft<4;++ft) acc[rt][ft]=zero;
    #pragma unroll
    for(int rt=0;rt<4;++rt)
      #pragma unroll
      for(int ft=0;ft<4;++ft)
        #pragma unroll
        for(int ks=0;ks<2;++ks)
          acc[rt][ft]=mfma16h(ka[rt][ks],pb[ft][ks],acc[rt][ft]);
    #pragma unroll
    for(int rt=0;rt<4;++rt)
      #pragma unroll
      for(int ft=0;ft<4;++ft)
        #pragma unroll
        for(int r=0;r<4;++r) m=fmaxf(m,acc[rt][ft][r]);
  }
  #pragma unroll
  for(int off=1;off<64;off<<=1) m=fmaxf(m,__shfl_xor(m,off));
  if(lane==0) red[w]=m;
  __syncthreads();
  if(tid==0){
    m=fmaxf(fmaxf(red[0],red[1]),fmaxf(red[2],red[3]));
    atomicMax(stab_ws,mapmax(m));
  }
}

// kp + ctx/ksum accumulation. grid = 512: 16 bh * 32 chunks of 256 rows,
// 8 iters. V raw loads hoisted before dd-GEMM. kp single-bf16 (consistent
// with ksum). No __syncthreads: kpt LDS regions are wave-local.
__global__ void __launch_bounds__(256,2) ctxK(const float* __restrict__ Kg,
    const float* __restrict__ Vg, const float* __restrict__ Pg,
    const unsigned* __restrict__ stab_ws, float* __restrict__ ctx_g,
    float* __restrict__ ksum_g){
  __shared__ __align__(16) bf16 kpt_h[256*40];
  int tid=threadIdx.x, w=tid>>6, lane=tid&63, l15=lane&15, g=lane>>4;
  int fb=w*64;
  int bh=blockIdx.x>>5, ch=blockIdx.x&31;
  long rowbase=(long)bh*N_ + ch*256;
  float stab=unmapmax(*stab_ws);
  bf16x8 pb_h[4][2], pb_l[4][2];
  load_P_frags(Pg,fb,l15,g,pb_h,pb_l);
  f32x4 zero={0.f,0.f,0.f,0.f};
  f32x4 cacc[4][4];
  #pragma unroll
  for(int mt=0;mt<4;++mt)
    #pragma unroll
    for(int et=0;et<4;++et) cacc[mt][et]=zero;
  float ksacc[4]={0.f,0.f,0.f,0.f};
  #pragma unroll 1
  for(int it=0;it<8;++it){
    long n0=rowbase+it*32;
    // K a-frags (split) + row sums of squares
    bf16x8 ka_h[2][2], ka_l[2][2];
    float dsq[2];
    #pragma unroll
    for(int rt=0;rt<2;++rt){
      float ss=0.f;
      #pragma unroll
      for(int ks=0;ks<2;++ks){
        float x[8]; ld8(&Kg[(n0+16*rt+l15)*64+32*ks+8*g],x);
        #pragma unroll
        for(int i=0;i<8;++i) ss=fmaf(x[i],x[i],ss);
        split8(x,ka_h[rt][ks],ka_l[rt][ks]);
      }
      ss+=__shfl_xor(ss,16); ss+=__shfl_xor(ss,32);
      dsq[rt]=DSC*ss;
    }
    // V raw prefetch (hoisted: latency hidden under dd-GEMM + exp)
    float vx[4][8];
    #pragma unroll
    for(int et=0;et<4;++et)
      #pragma unroll
      for(int j=0;j<8;++j) vx[et][j]=Vg[(n0+8*g+j)*64+16*et+l15];
    // dd = K-hat @ P-hat^T (3-pass split)
    f32x4 dacc[2][4];
    #pragma unroll
    for(int rt=0;rt<2;++rt)
      #pragma unroll
      for(int ft=0;ft<4;++ft) dacc[rt][ft]=zero;
    #pragma unroll
    for(int rt=0;rt<2;++rt)
      #pragma unroll
      for(int ft=0;ft<4;++ft)
        #pragma unroll
        for(int ks=0;ks<2;++ks){
          dacc[rt][ft]=mfma16(ka_h[rt][ks],pb_h[ft][ks],dacc[rt][ft]);
          dacc[rt][ft]=mfma16(ka_h[rt][ks],pb_l[ft][ks],dacc[rt][ft]);
          dacc[rt][ft]=mfma16(ka_l[rt][ks],pb_h[ft][ks],dacc[rt][ft]);
        }
    float dg[2][4];
    #pragma unroll
    for(int rt=0;rt<2;++rt)
      #pragma unroll
      for(int r=0;r<4;++r) dg[rt][r]=__shfl(dsq[rt],4*g+r);
    // kp = RATIO*exp(dd - diag - stab) + REPS, rounded to bf16;
    // ksum accumulates the SAME rounded value (consistent features).
    #pragma unroll
    for(int rt=0;rt<2;++rt)
      #pragma unroll
      for(int ft=0;ft<4;++ft){
        int f=fb+16*ft+l15;
        #pragma unroll
        for(int r=0;r<4;++r){
          float kp=fmaf(RATIO,__expf(dacc[rt][ft][r]-dg[rt][r]-stab),REPS);
          bf16 hb=(bf16)kp;
          ksacc[ft]+=(float)hb;
          int nn=16*rt+4*g+r;
          kpt_h[f*40+nn]=hb;
        }
      }
    // V b-frags (split from prefetched registers)
    bf16x8 vb_h[4], vb_l[4];
    #pragma unroll
    for(int et=0;et<4;++et) split8(vx[et],vb_h[et],vb_l[et]);
    // ctx += kp_b^T @ V (kp single-plane x V split = 2-pass)
    #pragma unroll
    for(int mt=0;mt<4;++mt){
      bf16x8 a_h=*(const bf16x8*)&kpt_h[(fb+16*mt+l15)*40+8*g];
      #pragma unroll
      for(int et=0;et<4;++et){
        cacc[mt][et]=mfma16(a_h,vb_h[et],cacc[mt][et]);
        cacc[mt][et]=mfma16(a_h,vb_l[et],cacc[mt][et]);
      }
    }
  }
  float* cg=ctx_g+(long)bh*16384;
  #pragma unroll
  for(int mt=0;mt<4;++mt)
    #pragma unroll
    for(int et=0;et<4;++et)
      #pragma unroll
      for(int r=0;r<4;++r)
        atomicAdd(&cg[(fb+16*mt+4*g+r)*64+16*et+l15],cacc[mt][et][r]);
  #pragma unroll
  for(int ft=0;ft<4;++ft){
    float s=ksacc[ft];
    s+=__shfl_xor(s,16); s+=__shfl_xor(s,32);
    if(g==0) atomicAdd(&ksum_g[bh*256+fb+16*ft+l15],s);
  }
}

// fused qp + out. grid = 512: 16 bh * 32 chunks of 256 rows, 8 iters.
// Q LDS-staged double-buffer (global_load_lds, swizzled source);
// qp single-bf16 written via ds_write_b16 (no pack shfls).
__global__ void __launch_bounds__(256,2) qoK(const float* __restrict__ Qg,
    const float* __restrict__ Pg, const float* __restrict__ ctx_g,
    const float* __restrict__ ksum_g, float* __restrict__ outg){
  __shared__ float qstage[2][2048];          // 2 x 8KB staged Q tiles (swizzled)
  __shared__ __align__(16) bf16 qpt[32*264]; // bf16 qp plane, [n][f], stride 264
  __shared__ float rmaxl[4][32];
  __shared__ float denl[4][32];
  int tid=threadIdx.x, w=tid>>6, lane=tid&63, l15=lane&15, g=lane>>4;
  int fb=w*64;
  int bh=blockIdx.x>>5, ch=blockIdx.x&31;
  long rowbase=(long)bh*N_ + ch*256;

  // stage 32 rows of Q (8KB) into qstage[buf]; LDS dest is lane-linear
  // (wave-uniform base + lane*16), source group XOR-swizzled by row&15 so
  // the fragment-pattern reads below are conflict-free.
#define STAGEQ(bufv, n0s) do{                                            \
    int u0_=tid, u1_=tid+256;                                            \
    int r0_=u0_>>4, c0_=u0_&15, r1_=u1_>>4, c1_=u1_&15;                  \
    gload16(Qg+((n0s)+r0_)*64+((c0_^(r0_&15))<<2), &qstage[bufv][u0_*4]);\
    gload16(Qg+((n0s)+r1_)*64+((c1_^(r1_&15))<<2), &qstage[bufv][u1_*4]);\
  }while(0)
  // x[8] <- staged row rr, k-chunk ks (two swizzled b128 reads)
#define QREAD(xv, bufv, rr, ksv) do{                                     \
    int cc0_=(8*(ksv)+2*g)^((rr)&15);                                    \
    int cc1_=cc0_^1;                                                     \
    float4 a_=*(const float4*)&qstage[bufv][(rr)*64+cc0_*4];             \
    float4 b_=*(const float4*)&qstage[bufv][(rr)*64+cc1_*4];             \
    xv[0]=a_.x; xv[1]=a_.y; xv[2]=a_.z; xv[3]=a_.w;                      \
    xv[4]=b_.x; xv[5]=b_.y; xv[6]=b_.z; xv[7]=b_.w;                      \
  }while(0)

  bf16x8 pb_h[4][2], pb_l[4][2];
  load_P_frags(Pg,fb,l15,g,pb_h,pb_l);
  float ksv[4];
  #pragma unroll
  for(int ft=0;ft<4;++ft) ksv[ft]=ksum_g[bh*256+fb+16*ft+l15];
  // ctx b-frags for this wave's e-tile (et = w), split
  bf16x8 cb_h[8], cb_l[8];
  #pragma unroll
  for(int ks=0;ks<8;++ks){
    float x[8];
    #pragma unroll
    for(int j=0;j<8;++j) x[j]=ctx_g[(long)bh*16384+(32*ks+8*g+j)*64+16*w+l15];
    split8(x,cb_h[ks],cb_l[ks]);
  }
  f32x4 zero={0.f,0.f,0.f,0.f};
  int cur=0;
  STAGEQ(0, rowbase);
  __syncthreads();                     // drain staging for iter 0
  #pragma unroll 1
  for(int it=0;it<8;++it){
    long n0=rowbase+it*32;
    long np=(it==7)? rowbase : n0+32;  // last iter: dummy re-stage (harmless)
    STAGEQ(cur^1, np);                 // issue next tile; lands by next barrier
    // Q a-frags (split) + diag from staged LDS
    bf16x8 qa_h[2][2], qa_l[2][2];
    float dsq[2];
    #pragma unroll
    for(int rt=0;rt<2;++rt){
      float ss=0.f;
      #pragma unroll
      for(int ks=0;ks<2;++ks){
        float x[8]; QREAD(x,cur,16*rt+l15,ks);
        #pragma unroll
        for(int i=0;i<8;++i) ss=fmaf(x[i],x[i],ss);
        split8(x,qa_h[rt][ks],qa_l[rt][ks]);
      }
      ss+=__shfl_xor(ss,16); ss+=__shfl_xor(ss,32);
      dsq[rt]=DSC*ss;
    }
    f32x4 dacc[2][4];
    #pragma unroll
    for(int rt=0;rt<2;++rt)
      #pragma unroll
      for(int ft=0;ft<4;++ft) dacc[rt][ft]=zero;
    #pragma unroll
    for(int rt=0;rt<2;++rt)
      #pragma unroll
      for(int ft=0;ft<4;++ft)
        #pragma unroll
        for(int ks=0;ks<2;++ks){
          dacc[rt][ft]=mfma16(qa_h[rt][ks],pb_h[ft][ks],dacc[rt][ft]);
          dacc[rt][ft]=mfma16(qa_h[rt][ks],pb_l[ft][ks],dacc[rt][ft]);
          dacc[rt][ft]=mfma16(qa_l[rt][ks],pb_h[ft][ks],dacc[rt][ft]);
        }
    float dg[2][4];
    #pragma unroll
    for(int rt=0;rt<2;++rt)
      #pragma unroll
      for(int r=0;r<4;++r) dg[rt][r]=__shfl(dsq[rt],4*g+r);
    // per-wave rowmax over its f-strip
    #pragma unroll
    for(int rt=0;rt<2;++rt)
      #pragma unroll
      for(int r=0;r<4;++r){
        float m=fmaxf(fmaxf(dacc[rt][0][r],dacc[rt][1][r]),
                      fmaxf(dacc[rt][2][r],dacc[rt][3][r]));
        m=fmaxf(m,__shfl_xor(m,1)); m=fmaxf(m,__shfl_xor(m,2));
        m=fmaxf(m,__shfl_xor(m,4)); m=fmaxf(m,__shfl_xor(m,8));
        if(l15==0) rmaxl[w][16*rt+4*g+r]=m;
      }
    __syncthreads();   // rowmax planes ready (also fences staging of cur^1)
    // qp (rounded bf16), den partials from the SAME rounded value,
    // direct b16 writes into qpt[n][f]
    #pragma unroll
    for(int rt=0;rt<2;++rt)
      #pragma unroll
      for(int r=0;r<4;++r){
        int nn=16*rt+4*g+r;
        float rm=fmaxf(fmaxf(rmaxl[0][nn],rmaxl[1][nn]),
                       fmaxf(rmaxl[2][nn],rmaxl[3][nn]));
        float dp=0.f;
        #pragma unroll
        for(int ft=0;ft<4;++ft){
          float qp=fmaf(RATIO,__expf(dacc[rt][ft][r]-dg[rt][r]-rm),REPS);
          bf16 hb=(bf16)qp;
          dp=fmaf((float)hb,ksv[ft],dp);
          qpt[nn*264 + fb+16*ft+l15]=hb;
        }
        dp+=__shfl_xor(dp,1); dp+=__shfl_xor(dp,2);
        dp+=__shfl_xor(dp,4); dp+=__shfl_xor(dp,8);
        if(l15==0) denl[w][nn]=dp;
      }
    __syncthreads();   // qpt + denl ready
    // out = qp_b @ ctx (single-plane qp x split ctx = 2-pass)
    f32x4 oacc[2]; oacc[0]=zero; oacc[1]=zero;
    #pragma unroll
    for(int ks=0;ks<8;++ks)
      #pragma unroll
      for(int mt=0;mt<2;++mt){
        bf16x8 a_h=*(const bf16x8*)&qpt[(16*mt+l15)*264+32*ks+8*g];
        oacc[mt]=mfma16(a_h,cb_h[ks],oacc[mt]);
        oacc[mt]=mfma16(a_h,cb_l[ks],oacc[mt]);
      }
    #pragma unroll
    for(int mt=0;mt<2;++mt)
      #pragma unroll
      for(int r=0;r<4;++r){
        int nn=16*mt+4*g+r;
        float den=denl[0][nn]+denl[1][nn]+denl[2][nn]+denl[3][nn];
        outg[(n0+nn)*64+16*w+l15]=oacc[mt][r]/den;
      }
    cur^=1;
  }
#undef STAGEQ
#undef QREAD
}

// ---------------- host ----------------

extern "C" void kernel_launch(void* const* d_in, const int* in_sizes, int n_in,
                              void* d_out, int out_size, void* d_ws, size_t ws_size,
                              hipStream_t stream) {
  (void)in_sizes; (void)n_in; (void)out_size; (void)ws_size;
  const float* q = (const float*)d_in[0];
  const float* k = (const float*)d_in[1];
  const float* v = (const float*)d_in[2];
  const float* P = (const float*)d_in[3];
  float* out = (float*)d_out;

  unsigned* stab = (unsigned*)d_ws;
  float* ctx  = (float*)d_ws + CTX_W;
  float* ksum = (float*)d_ws + KSUM_W;

  hipLaunchKernelGGL(initK, dim3(256), dim3(256), 0, stream, (unsigned*)d_ws);
  hipLaunchKernelGGL(stabK, dim3(512), dim3(256), 0, stream, k, P, stab);
  hipLaunchKernelGGL(ctxK, dim3(512), dim3(256), 0, stream, k, v, P, stab, ctx, ksum);
  hipLaunchKernelGGL(qoK, dim3(512), dim3(256), 0, stream, q, P, ctx, ksum, out);
}